// Round 10
// baseline (351.021 us; speedup 1.0000x reference)
//
#include <hip/hip_runtime.h>

typedef unsigned int uint;
typedef unsigned short ushort;
typedef __attribute__((ext_vector_type(8))) short short8;
typedef __attribute__((ext_vector_type(4))) float f32x4;
typedef __attribute__((ext_vector_type(4))) int i32x4;

#define DIM 64
#define MAXDEG 48
#define NBUCKET 8

__device__ __forceinline__ ushort f2bf(float f) {
    uint u = __float_as_uint(f);
    u += 0x7fffu + ((u >> 16) & 1u);   // round-to-nearest-even
    return (ushort)(u >> 16);
}
__device__ __forceinline__ float bf2f(ushort h) {
    return __uint_as_float(((uint)h) << 16);
}

// ---- fp32 -> bf16 convert (x -> hA) ----
__global__ __launch_bounds__(256) void f32_to_bf16(
    const float4* __restrict__ in, ushort4* __restrict__ out, int n4)
{
    int i = blockIdx.x * blockDim.x + threadIdx.x;
    if (i >= n4) return;
    float4 v = in[i];
    ushort4 o;
    o.x = f2bf(v.x); o.y = f2bf(v.y); o.z = f2bf(v.z); o.w = f2bf(v.w);
    out[i] = o;
}

// ---- pack weights into per-lane fragment order (once per launch) ----
__global__ void pack_weights(
    const float* __restrict__ W1, const float* __restrict__ W2,
    const float* __restrict__ Wf, ushort* __restrict__ wp, ushort* __restrict__ lp)
{
    const int lane = threadIdx.x;          // 64 threads
    const int c = lane & 15, g = lane >> 4;
    if (blockIdx.x < 3) {
        const int l = blockIdx.x;
        const float* w1 = W1 + (size_t)l * 4096;
        const float* w2 = W2 + (size_t)l * 4096;
        ushort* d0 = wp + ((size_t)(l * 2 + 0) * 64 + lane) * 64;
        ushort* d1 = wp + ((size_t)(l * 2 + 1) * 64 + lane) * 64;
        for (int kc = 0; kc < 2; ++kc)
            for (int t = 0; t < 4; ++t)
                for (int j = 0; j < 8; ++j) {
                    int src = (kc * 32 + g * 8 + j) * 64 + t * 16 + c;
                    d0[(kc * 4 + t) * 8 + j] = f2bf(w1[src]);
                    d1[(kc * 4 + t) * 8 + j] = f2bf(w2[src]);
                }
    } else {
        for (int kc = 0; kc < 2; ++kc)
            for (int t = 0; t < 4; ++t)
                for (int j = 0; j < 8; ++j) {
                    float wv = Wf[(kc * 32 + g * 8 + j) * 64 + t * 16 + c];
                    ushort h = f2bf(wv);
                    ushort l = f2bf(wv - bf2f(h));
                    lp[(size_t)lane * 128 + ((0 * 2 + kc) * 4 + t) * 8 + j] = h;
                    lp[(size_t)lane * 128 + ((1 * 2 + kc) * 4 + t) * 8 + j] = l;
                }
    }
}

// ---- msgs MLP: out = relu(in@W1 + b1)@W2 + b2, bf16, prepacked weights ----
__global__ __launch_bounds__(256, 4) void mlp_mfma(
    const ushort* __restrict__ in, ushort* __restrict__ out,
    const ushort* __restrict__ wp,
    const float* __restrict__ b1, const float* __restrict__ b2,
    int ntiles)
{
    __shared__ __align__(16) ushort lds[4][16 * 72];
    const int lane = threadIdx.x & 63;
    const int wid  = threadIdx.x >> 6;
    const int c = lane & 15, g = lane >> 4;
    ushort* myl = &lds[wid][0];

    const ushort* w0 = wp + (size_t)lane * 64;
    const ushort* w1p = wp + (size_t)(64 + lane) * 64;
    short8 wf[2][2][4];
#pragma unroll
    for (int kc = 0; kc < 2; ++kc)
#pragma unroll
        for (int t = 0; t < 4; ++t) {
            wf[0][kc][t] = *(const short8*)(w0 + (kc * 4 + t) * 8);
            wf[1][kc][t] = *(const short8*)(w1p + (kc * 4 + t) * 8);
        }
    float bc1[4], bc2[4];
#pragma unroll
    for (int t = 0; t < 4; ++t) { bc1[t] = b1[t * 16 + c]; bc2[t] = b2[t * 16 + c]; }

    const int gw = (int)((blockIdx.x * blockDim.x + threadIdx.x) >> 6);
    const int nw = (int)((gridDim.x * blockDim.x) >> 6);

    for (int tile = gw; tile < ntiles; tile += nw) {
        const ushort* rp = in + (size_t)(tile * 16 + c) * DIM;
        short8 a0 = *(const short8*)(rp + g * 8);
        short8 a1 = *(const short8*)(rp + 32 + g * 8);

        f32x4 acc[4];
#pragma unroll
        for (int t = 0; t < 4; ++t) {
            f32x4 z = {0.f, 0.f, 0.f, 0.f};
            z = __builtin_amdgcn_mfma_f32_16x16x32_bf16(a0, wf[0][0][t], z, 0, 0, 0);
            z = __builtin_amdgcn_mfma_f32_16x16x32_bf16(a1, wf[0][1][t], z, 0, 0, 0);
            acc[t] = z;
        }
#pragma unroll
        for (int t = 0; t < 4; ++t)
#pragma unroll
            for (int r = 0; r < 4; ++r) {
                float v = fmaxf(acc[t][r] + bc1[t], 0.f);
                myl[(4 * g + r) * 72 + 16 * t + c] = f2bf(v);
            }
        short8 h0 = *(const short8*)(myl + c * 72 + g * 8);
        short8 h1 = *(const short8*)(myl + c * 72 + 32 + g * 8);

#pragma unroll
        for (int t = 0; t < 4; ++t) {
            f32x4 z = {0.f, 0.f, 0.f, 0.f};
            z = __builtin_amdgcn_mfma_f32_16x16x32_bf16(h0, wf[1][0][t], z, 0, 0, 0);
            z = __builtin_amdgcn_mfma_f32_16x16x32_bf16(h1, wf[1][1][t], z, 0, 0, 0);
#pragma unroll
            for (int r = 0; r < 4; ++r)
                myl[(4 * g + r) * 72 + 16 * t + c] = f2bf(z[r] + bc2[t]);
        }
        const ushort* lp2 = myl + (lane >> 2) * 72 + (lane & 3) * 8;
        short8 ov0 = *(const short8*)lp2;
        short8 ov1 = *(const short8*)(lp2 + 32);
        ushort* op = out + (size_t)(tile * 16 + (lane >> 2)) * DIM + (lane & 3) * 8;
        *(short8*)op = ov0;
        *(short8*)(op + 32) = ov1;
    }
}

// ---- FUSED combine: hA[tile] = mlp(hA[tile] + sum_{nbr} m[nbr]) ----
// Gather accumulates in fp32 directly into A-fragment layout: lane (c,g)
// owns row c, cols g*8+j and 32+g*8+j. In-place hA update is safe: each
// tile's rows are read/written only by the wave owning the tile; other
// waves read only m (=hB). Removes the t buffer round-trip (25.6MB/layer).
__global__ __launch_bounds__(256, 3) void mlp_agg_mfma(
    ushort* __restrict__ hA, const ushort* __restrict__ m,
    const ushort* __restrict__ wp,
    const float* __restrict__ b1, const float* __restrict__ b2,
    const int* __restrict__ ell, const int* __restrict__ cnt,
    int ntiles)
{
    __shared__ __align__(16) ushort lds[4][16 * 72];
    const int lane = threadIdx.x & 63;
    const int wid  = threadIdx.x >> 6;
    const int c = lane & 15, g = lane >> 4;
    ushort* myl = &lds[wid][0];

    const ushort* w0 = wp + (size_t)lane * 64;
    const ushort* w1p = wp + (size_t)(64 + lane) * 64;
    short8 wf[2][2][4];
#pragma unroll
    for (int kc = 0; kc < 2; ++kc)
#pragma unroll
        for (int t = 0; t < 4; ++t) {
            wf[0][kc][t] = *(const short8*)(w0 + (kc * 4 + t) * 8);
            wf[1][kc][t] = *(const short8*)(w1p + (kc * 4 + t) * 8);
        }
    float bc1[4], bc2[4];
#pragma unroll
    for (int t = 0; t < 4; ++t) { bc1[t] = b1[t * 16 + c]; bc2[t] = b2[t * 16 + c]; }

    const int gw = (int)((blockIdx.x * blockDim.x + threadIdx.x) >> 6);
    const int nw = (int)((gridDim.x * blockDim.x) >> 6);

    for (int tile = gw; tile < ntiles; tile += nw) {
        const int row = tile * 16 + c;
        const ushort* rp = hA + (size_t)row * DIM;
        short8 a0 = *(const short8*)(rp + g * 8);
        short8 a1 = *(const short8*)(rp + 32 + g * 8);

        float accL[8], accH[8];
#pragma unroll
        for (int j = 0; j < 8; ++j) {
            accL[j] = bf2f((ushort)a0[j]);
            accH[j] = bf2f((ushort)a1[j]);
        }

        int deg = cnt[row];
        deg = deg < MAXDEG ? deg : MAXDEG;
        const int* el = ell + (size_t)row * MAXDEG;
        const int go = g * 8;

        int i = 0;
        for (; i + 4 <= deg; i += 4) {
            int4 q = *(const int4*)(el + i);
            const ushort* p0 = m + (size_t)q.x * DIM + go;
            const ushort* p1 = m + (size_t)q.y * DIM + go;
            const ushort* p2 = m + (size_t)q.z * DIM + go;
            const ushort* p3 = m + (size_t)q.w * DIM + go;
            short8 r0L = *(const short8*)p0, r0H = *(const short8*)(p0 + 32);
            short8 r1L = *(const short8*)p1, r1H = *(const short8*)(p1 + 32);
            short8 r2L = *(const short8*)p2, r2H = *(const short8*)(p2 + 32);
            short8 r3L = *(const short8*)p3, r3H = *(const short8*)(p3 + 32);
#pragma unroll
            for (int j = 0; j < 8; ++j) {
                accL[j] += (bf2f((ushort)r0L[j]) + bf2f((ushort)r1L[j]))
                         + (bf2f((ushort)r2L[j]) + bf2f((ushort)r3L[j]));
                accH[j] += (bf2f((ushort)r0H[j]) + bf2f((ushort)r1H[j]))
                         + (bf2f((ushort)r2H[j]) + bf2f((ushort)r3H[j]));
            }
        }
        for (; i < deg; ++i) {
            const ushort* p = m + (size_t)el[i] * DIM + go;
            short8 rL = *(const short8*)p, rH = *(const short8*)(p + 32);
#pragma unroll
            for (int j = 0; j < 8; ++j) {
                accL[j] += bf2f((ushort)rL[j]);
                accH[j] += bf2f((ushort)rH[j]);
            }
        }
        // fp32 acc -> bf16 A-frags (same rounding the old t-store had)
        short8 t0, t1;
#pragma unroll
        for (int j = 0; j < 8; ++j) {
            t0[j] = (short)f2bf(accL[j]);
            t1[j] = (short)f2bf(accH[j]);
        }

        f32x4 acc[4];
#pragma unroll
        for (int t = 0; t < 4; ++t) {
            f32x4 z = {0.f, 0.f, 0.f, 0.f};
            z = __builtin_amdgcn_mfma_f32_16x16x32_bf16(t0, wf[0][0][t], z, 0, 0, 0);
            z = __builtin_amdgcn_mfma_f32_16x16x32_bf16(t1, wf[0][1][t], z, 0, 0, 0);
            acc[t] = z;
        }
#pragma unroll
        for (int t = 0; t < 4; ++t)
#pragma unroll
            for (int r = 0; r < 4; ++r) {
                float v = fmaxf(acc[t][r] + bc1[t], 0.f);
                myl[(4 * g + r) * 72 + 16 * t + c] = f2bf(v);
            }
        short8 h0 = *(const short8*)(myl + c * 72 + g * 8);
        short8 h1 = *(const short8*)(myl + c * 72 + 32 + g * 8);

#pragma unroll
        for (int t = 0; t < 4; ++t) {
            f32x4 z = {0.f, 0.f, 0.f, 0.f};
            z = __builtin_amdgcn_mfma_f32_16x16x32_bf16(h0, wf[1][0][t], z, 0, 0, 0);
            z = __builtin_amdgcn_mfma_f32_16x16x32_bf16(h1, wf[1][1][t], z, 0, 0, 0);
#pragma unroll
            for (int r = 0; r < 4; ++r)
                myl[(4 * g + r) * 72 + 16 * t + c] = f2bf(z[r] + bc2[t]);
        }
        const ushort* lp2 = myl + (lane >> 2) * 72 + (lane & 3) * 8;
        short8 ov0 = *(const short8*)lp2;
        short8 ov1 = *(const short8*)(lp2 + 32);
        ushort* op = hA + (size_t)(tile * 16 + (lane >> 2)) * DIM + (lane & 3) * 8;
        *(short8*)op = ov0;
        *(short8*)(op + 32) = ov1;
    }
}

// ---- final projection: out_f32 = in_bf16 @ Wf + bf (prepacked hi/lo) ----
__global__ __launch_bounds__(256) void linear_mfma(
    const ushort* __restrict__ in, float* __restrict__ out,
    const ushort* __restrict__ lpw, const float* __restrict__ bg, int ntiles)
{
    const int lane = threadIdx.x & 63;
    const int c = lane & 15, g = lane >> 4;

    short8 wf[2][2][4];
#pragma unroll
    for (int s = 0; s < 2; ++s)
#pragma unroll
        for (int kc = 0; kc < 2; ++kc)
#pragma unroll
            for (int t = 0; t < 4; ++t)
                wf[s][kc][t] = *(const short8*)(lpw + (size_t)lane * 128 + ((s * 2 + kc) * 4 + t) * 8);
    float bc[4];
#pragma unroll
    for (int t = 0; t < 4; ++t) bc[t] = bg[t * 16 + c];

    const int gw = (int)((blockIdx.x * blockDim.x + threadIdx.x) >> 6);
    const int nw = (int)((gridDim.x * blockDim.x) >> 6);

    for (int tile = gw; tile < ntiles; tile += nw) {
        const ushort* rp = in + (size_t)(tile * 16 + c) * DIM;
        short8 a0 = *(const short8*)(rp + g * 8);
        short8 a1 = *(const short8*)(rp + 32 + g * 8);
#pragma unroll
        for (int t = 0; t < 4; ++t) {
            f32x4 z = {0.f, 0.f, 0.f, 0.f};
            z = __builtin_amdgcn_mfma_f32_16x16x32_bf16(a0, wf[0][0][t], z, 0, 0, 0);
            z = __builtin_amdgcn_mfma_f32_16x16x32_bf16(a1, wf[0][1][t], z, 0, 0, 0);
            z = __builtin_amdgcn_mfma_f32_16x16x32_bf16(a0, wf[1][0][t], z, 0, 0, 0);
            z = __builtin_amdgcn_mfma_f32_16x16x32_bf16(a1, wf[1][1][t], z, 0, 0, 0);
#pragma unroll
            for (int r = 0; r < 4; ++r)
                out[(size_t)(tile * 16 + 4 * g + r) * DIM + 16 * t + c] = z[r] + bc[t];
        }
    }
}

// ---- ELL adjacency build, bucketed by XCD; edge stream via NT loads ----
__global__ __launch_bounds__(256) void fill_ell_bucketed(
    const int* __restrict__ rowi, const int* __restrict__ coli,
    int* __restrict__ cnt, int* __restrict__ ell, int E, int nper)
{
    const int bucket = blockIdx.x & (NBUCKET - 1);
    const int bpb = gridDim.x / NBUCKET;
    const int bidx = blockIdx.x >> 3;
    const int lo = bucket * nper;
    const int hi = lo + nper;
    const int stride = bpb * 256;
    const int e4n = E >> 2;

    for (int i = bidx * 256 + threadIdx.x; i < e4n; i += stride) {
        i32x4 r4 = __builtin_nontemporal_load((const i32x4*)rowi + i);
        i32x4 c4 = __builtin_nontemporal_load((const i32x4*)coli + i);
#pragma unroll
        for (int u = 0; u < 4; ++u) {
            int r = r4[u];
            if (r >= lo && r < hi) {
                int slot = atomicAdd(&cnt[r], 1);
                if (slot < MAXDEG) ell[(size_t)r * MAXDEG + slot] = c4[u];
            }
        }
    }
}

extern "C" void kernel_launch(void* const* d_in, const int* in_sizes, int n_in,
                              void* d_out, int out_size, void* d_ws, size_t ws_size,
                              hipStream_t stream)
{
    const float* x  = (const float*)d_in[0];
    const int*   ei = (const int*)d_in[1];
    const float* W1 = (const float*)d_in[2];
    const float* b1 = (const float*)d_in[3];
    const float* W2 = (const float*)d_in[4];
    const float* b2 = (const float*)d_in[5];
    const float* Wf = (const float*)d_in[6];
    const float* bf = (const float*)d_in[7];
    float* out = (float*)d_out;

    const int N = in_sizes[0] / DIM;
    const int E = in_sizes[1] / 2;
    const int NT = N / 16;

    ushort* hA = (ushort*)d_ws;               // h   (12.8 MB)
    ushort* hB = hA + (size_t)N * DIM;        // m   (12.8 MB)
    int* cnt = (int*)(hB + (size_t)N * DIM);
    int* ell = cnt + N;                       // N * MAXDEG ints (19.2 MB)
    ushort* wpack = (ushort*)(ell + (size_t)N * MAXDEG);  // 6*64*64 shorts
    ushort* lpack = wpack + 6 * 64 * 64;                  // 64*128 shorts

    f32_to_bf16<<<(N * DIM / 4 + 255) / 256, 256, 0, stream>>>(
        (const float4*)x, (ushort4*)hA, N * DIM / 4);
    (void)hipMemsetAsync(cnt, 0, (size_t)N * sizeof(int), stream);
    fill_ell_bucketed<<<4096, 256, 0, stream>>>(
        ei, ei + E, cnt, ell, E, (N + NBUCKET - 1) / NBUCKET);
    pack_weights<<<4, 64, 0, stream>>>(W1, W2, Wf, wpack, lpack);

    for (int l = 0; l < 3; ++l) {
        const ushort* wp = wpack + (size_t)l * 2 * 64 * 64;
        const float* bb1 = b1 + (size_t)l * DIM;
        const float* bb2 = b2 + (size_t)l * DIM;
        mlp_mfma<<<1024, 256, 0, stream>>>(hA, hB, wp, bb1, bb2, NT);
        mlp_agg_mfma<<<1024, 256, 0, stream>>>(hA, hB, wp, bb1, bb2, ell, cnt, NT);
    }
    linear_mfma<<<1024, 256, 0, stream>>>(hA, out, lpack, bf, NT);
}